// Round 11
// baseline (135.820 us; speedup 1.0000x reference)
//
#include <hip/hip_runtime.h>
#include <hip/hip_bf16.h>

#define N_NODES 50000
#define N_EDGES 640000
#define C 128            // IN_C == HID
#define NB 196           // dst buckets of 256 nodes (50000 <= 196*256)
#define BCAP 4096        // fixed edge capacity per bucket (mean 3277, +14 sigma)
#define DCAP 96          // per-node edge-list capacity (mean 12.8, Poisson +~20 sigma)
#define NTILES (N_NODES / 16)                               // 3125
#define PART_BLOCKS 625  // partition blocks in fused_pp
#define PRE_BLOCKS 1024  // precomp blocks in fused_pp

typedef __bf16 bf16x8 __attribute__((ext_vector_type(8)));
typedef __bf16 bf16x4 __attribute__((ext_vector_type(4)));
typedef float  f32x4  __attribute__((ext_vector_type(4)));
typedef float  f32x2  __attribute__((ext_vector_type(2)));
typedef unsigned int u32x4 __attribute__((ext_vector_type(4)));

// ---- d_ws layout (byte offsets) ----
#define WS_GCUR  0          // NB ints (bucket cursors; zeroed by memset)
#define WS_REC   1024       // NB*BCAP u32 packed records (src | dstLocal<<16)
#define WS_HDST  3212288    // N*C bf16 (Hdst + bias)
#define WS_HSRC8 16012288   // N*C fp8 e4m3 (6.4 MB)
#define WS_AGGR  22412288   // N*C bf16 (aggregation result)
// total ~35.2 MB

// XOR-swizzle for [16][128]-short LDS tiles (2-way residual conflict = free).
__device__ __forceinline__ int swzS(int row, int soff) {
    return row * 128 + (soff ^ ((row & 7) << 3));
}
// [16][256]-short variant (node-update staging)
__device__ __forceinline__ int swz8(int row, int soff) {
    return row * 256 + (soff ^ ((row & 7) << 3));
}

// ---------------------------------------------------------------------------
// fused_pp: blocks [0,625) partition edges into bucket slots;
//           blocks [625,1649) precompute Hsrc (fp8) / Hdst (bf16).
// The two phases touch disjoint data — one dispatch overlaps them.
// ---------------------------------------------------------------------------
__global__ __launch_bounds__(512) void fused_pp_kernel(
    const float* __restrict__ embed, const float* __restrict__ Wmsg,
    const float* __restrict__ bmsg,  unsigned char* __restrict__ Hsrc8,
    __bf16* __restrict__ Hdst, const int* __restrict__ eidx,
    int* __restrict__ gcur, unsigned* __restrict__ rec)
{
    __shared__ int   cnt[NB];
    __shared__ int   base[NB];
    __shared__ short lds[16 * 128];

    if (blockIdx.x < PART_BLOCKS) {
        // ---- partition phase: 1024 edges/block, LDS counters ----
        const int t = threadIdx.x;
        if (t < NB) cnt[t] = 0;
        __syncthreads();
        const int e0 = blockIdx.x * 1024;
        int lrank[2], bb[2];
        unsigned prec[2];
        #pragma unroll
        for (int k = 0; k < 2; ++k) {
            const int e = e0 + k * 512 + t;
            const int r = eidx[e], c = eidx[N_EDGES + e];
            bb[k]   = c >> 8;
            prec[k] = (unsigned)r | ((unsigned)(c & 255) << 16);
            lrank[k] = atomicAdd(&cnt[bb[k]], 1);
        }
        __syncthreads();
        if (t < NB) base[t] = t * BCAP + atomicAdd(&gcur[t], cnt[t]);
        __syncthreads();
        #pragma unroll
        for (int k = 0; k < 2; ++k)
            rec[base[bb[k]] + lrank[k]] = prec[k];
        return;
    }

    // ---- precomp phase ----
    const int t = threadIdx.x, lane = t & 63, wave = t >> 6;
    const int chbase = wave * 16, q = lane >> 4, nr = lane & 15;
    const int ch = chbase + nr;

    bf16x8 aS[4], aD[4];
    #pragma unroll
    for (int ks = 0; ks < 4; ++ks)
        #pragma unroll
        for (int i = 0; i < 8; ++i) {
            const int k = ks * 32 + q * 8 + i;
            aS[ks][i] = (__bf16)Wmsg[k * C + ch];
            aD[ks][i] = (__bf16)Wmsg[(128 + k) * C + ch];
        }
    float bias[4];
    #pragma unroll
    for (int r = 0; r < 4; ++r) bias[r] = bmsg[chbase + q * 4 + r];

    for (int nt = blockIdx.x - PART_BLOCKS; nt < NTILES; nt += PRE_BLOCKS) {
        const int n0 = nt * 16;
        {   // stage 16 nodes x 128 feats: f32 -> bf16 LDS
            const int row = t >> 5, seg = t & 31;
            const float4 f = *(const float4*)(embed + (long)(n0 + row) * C + seg * 4);
            bf16x4 v;
            v[0]=(__bf16)f.x; v[1]=(__bf16)f.y; v[2]=(__bf16)f.z; v[3]=(__bf16)f.w;
            *(bf16x4*)(&lds[swzS(row, seg * 4)]) = v;
        }
        __syncthreads();

        f32x4 hs = {0.f,0.f,0.f,0.f}, hd = {0.f,0.f,0.f,0.f};
        #pragma unroll
        for (int ks = 0; ks < 4; ++ks) {
            const bf16x8 b = *(const bf16x8*)(&lds[swzS(nr, ks * 32 + q * 8)]);
            hs = __builtin_amdgcn_mfma_f32_16x16x32_bf16(aS[ks], b, hs, 0, 0, 0);
            hd = __builtin_amdgcn_mfma_f32_16x16x32_bf16(aD[ks], b, hd, 0, 0, 0);
        }
        __syncthreads();

        const int node = n0 + nr;            // D: col=node, row(q*4+r)=ch
        int w8 = 0;
        w8 = __builtin_amdgcn_cvt_pk_fp8_f32(hs[0], hs[1], w8, false);
        w8 = __builtin_amdgcn_cvt_pk_fp8_f32(hs[2], hs[3], w8, true);
        *(unsigned*)(Hsrc8 + (long)node * C + chbase + q * 4) = (unsigned)w8;
        bf16x4 vd;
        #pragma unroll
        for (int r = 0; r < 4; ++r) vd[r] = (__bf16)(hd[r] + bias[r]);
        *(bf16x4*)(Hdst + (long)node * C + chbase + q * 4) = vd;
    }
}

// ---------------------------------------------------------------------------
// Aggregate: block owns 4 consecutive nodes (one bucket slice; grid 12500 =
// 196 buckets x 64 blocks, 256-node-aligned). Phase A: filter the bucket's
// records for our 4 dstLocals into LDS edge lists (records L2-hot, read by
// 64 blocks). Phase B: one node per wave, 4 groups x 16 lanes (8 ch/lane),
// depth-2 pipeline, fp8 Hsrc gathers. Writes aggrB (bf16) once.
// ---------------------------------------------------------------------------
__global__ __launch_bounds__(256) void aggr_kernel(
    const unsigned char* __restrict__ Hsrc8, const __bf16* __restrict__ Hdst,
    const float*  __restrict__ pos,  const float* __restrict__ Wmsg,
    const int*    __restrict__ gcur, const unsigned* __restrict__ rec,
    __bf16* __restrict__ aggrB)
{
    __shared__ int lcnt[4];
    __shared__ unsigned short llist[4 * DCAP];

    const int t = threadIdx.x, lane = t & 63, wv = t >> 6;
    const int b   = blockIdx.x >> 6;          // bucket
    const int myG = (blockIdx.x & 63) << 2;   // first dstLocal of this block
    if (t < 4) lcnt[t] = 0;
    __syncthreads();

    {   // Phase A: filter bucket records for dstLocal in [myG, myG+4)
        const int r0 = b * BCAP, r1 = r0 + gcur[b];
        for (int i = r0 + t; i < r1; i += 256) {
            const unsigned rc = rec[i];
            const int dl = (int)(rc >> 16);
            if ((dl & ~3) == myG) {
                const int idx = dl & 3;
                const int p = atomicAdd(&lcnt[idx], 1);
                if (p < DCAP) llist[idx * DCAP + p] = (unsigned short)(rc & 0xFFFFu);
            }
        }
    }
    __syncthreads();

    // Phase B: wave wv aggregates node n
    const int g   = lane >> 4;           // edge sub-group 0..3
    const int c8  = (lane & 15) * 8;     // channel base (8 ch/lane)
    const int n   = blockIdx.x * 4 + wv; // < 50000 by construction
    const int cnt = min(lcnt[wv], DCAP);

    float w2[8], hd[8], acc[8];
    *(f32x4*)&w2[0] = *(const f32x4*)(Wmsg + 256 * C + c8);
    *(f32x4*)&w2[4] = *(const f32x4*)(Wmsg + 256 * C + c8 + 4);
    {   // unpack Hdst row slice (bf16 -> f32)
        const u32x4 hdb = *(const u32x4*)(Hdst + (long)n * C + c8);
        #pragma unroll
        for (int k = 0; k < 4; ++k) {
            hd[2*k]   = __uint_as_float(hdb[k] << 16);
            hd[2*k+1] = __uint_as_float(hdb[k] & 0xffff0000u);
        }
    }
    const float px = pos[n * 3], py = pos[n * 3 + 1], pz = pos[n * 3 + 2];
    #pragma unroll
    for (int j = 0; j < 8; ++j) acc[j] = 0.f;

    if (cnt > 0) {
        const unsigned short* myl = &llist[wv * DCAP];
        const int last = cnt - 1;
        int s0 = myl[min(g,     last)];
        int s1 = myl[min(4 + g, last)];
        for (int j = 0; j < cnt; j += 8) {
            // issue both halves' gathers, then prefetch next ids
            const float qx0 = pos[s0*3], qy0 = pos[s0*3+1], qz0 = pos[s0*3+2];
            const uint2 hu0 = *(const uint2*)(Hsrc8 + (long)s0 * C + c8);
            const float qx1 = pos[s1*3], qy1 = pos[s1*3+1], qz1 = pos[s1*3+2];
            const uint2 hu1 = *(const uint2*)(Hsrc8 + (long)s1 * C + c8);
            const int sn0 = myl[min(j + 8  + g, last)];
            const int sn1 = myl[min(j + 12 + g, last)];

            {   // half 0: edge j+g
                const float dx = qx0 - px, dy = qy0 - py, dz = qz0 - pz;
                const float d  = dx * dx + dy * dy + dz * dz;
                const bool valid = (j + g) < cnt;
                const f32x2 p0 = __builtin_amdgcn_cvt_pk_f32_fp8((int)hu0.x, false);
                const f32x2 p1 = __builtin_amdgcn_cvt_pk_f32_fp8((int)hu0.x, true);
                const f32x2 p2 = __builtin_amdgcn_cvt_pk_f32_fp8((int)hu0.y, false);
                const f32x2 p3 = __builtin_amdgcn_cvt_pk_f32_fp8((int)hu0.y, true);
                const float hs[8] = {p0[0],p0[1],p1[0],p1[1],p2[0],p2[1],p3[0],p3[1]};
                #pragma unroll
                for (int j2 = 0; j2 < 8; ++j2) {
                    const float v = fmaxf(hs[j2] + hd[j2] + d * w2[j2], 0.f);
                    acc[j2] += valid ? v : 0.f;
                }
            }
            {   // half 1: edge j+4+g
                const float dx = qx1 - px, dy = qy1 - py, dz = qz1 - pz;
                const float d  = dx * dx + dy * dy + dz * dz;
                const bool valid = (j + 4 + g) < cnt;
                const f32x2 p0 = __builtin_amdgcn_cvt_pk_f32_fp8((int)hu1.x, false);
                const f32x2 p1 = __builtin_amdgcn_cvt_pk_f32_fp8((int)hu1.x, true);
                const f32x2 p2 = __builtin_amdgcn_cvt_pk_f32_fp8((int)hu1.y, false);
                const f32x2 p3 = __builtin_amdgcn_cvt_pk_f32_fp8((int)hu1.y, true);
                const float hs[8] = {p0[0],p0[1],p1[0],p1[1],p2[0],p2[1],p3[0],p3[1]};
                #pragma unroll
                for (int j2 = 0; j2 < 8; ++j2) {
                    const float v = fmaxf(hs[j2] + hd[j2] + d * w2[j2], 0.f);
                    acc[j2] += valid ? v : 0.f;
                }
            }
            s0 = sn0; s1 = sn1;
        }
    }
    #pragma unroll
    for (int j = 0; j < 8; ++j) {        // combine the 4 edge groups
        acc[j] += __shfl_xor(acc[j], 16);
        acc[j] += __shfl_xor(acc[j], 32);
    }
    if (lane < 16) {
        bf16x8 v;
        #pragma unroll
        for (int j = 0; j < 8; ++j) v[j] = (__bf16)acc[j];
        *(bf16x8*)(aggrB + (long)n * C + c8) = v;
    }
}

// ---------------------------------------------------------------------------
// Node update: out = embed @ W_res + relu([embed, aggr] @ W_upd + b_upd)
// One 16-node tile per block (grid = NTILES).
// ---------------------------------------------------------------------------
__global__ __launch_bounds__(512) void node_upd_kernel(
    const float* __restrict__ embed, const __bf16* __restrict__ aggrB,
    const float* __restrict__ Wres,  const float* __restrict__ Wupd,
    const float* __restrict__ bupd,  float* __restrict__ out)
{
    __shared__ short ldsF[16 * 256];

    const int t = threadIdx.x, lane = t & 63, wave = t >> 6;
    const int chbase = wave * 16, q = lane >> 4, nr = lane & 15;

    bf16x8 aU[8], aR[4];
    {
        const int ch = chbase + nr;
        #pragma unroll
        for (int ks = 0; ks < 8; ++ks)
            #pragma unroll
            for (int i = 0; i < 8; ++i)
                aU[ks][i] = (__bf16)Wupd[(ks*32 + q*8 + i) * C + ch];
        #pragma unroll
        for (int ks = 0; ks < 4; ++ks)
            #pragma unroll
            for (int i = 0; i < 8; ++i)
                aR[ks][i] = (__bf16)Wres[(ks*32 + q*8 + i) * C + ch];
    }
    float bu[4];
    #pragma unroll
    for (int r = 0; r < 4; ++r) bu[r] = bupd[chbase + q*4 + r];

    const int n0 = blockIdx.x * 16;
    {   // stage [embed(f32->bf16) | aggr(bf16 copy)] for 16 nodes
        const int nn = t >> 5, seg = t & 31;
        bf16x8 v;
        if (seg < 16) {
            const float* src = embed + (long)(n0 + nn) * C + seg * 8;
            const float4 f0 = *(const float4*)src;
            const float4 f1 = *(const float4*)(src + 4);
            v[0]=(__bf16)f0.x; v[1]=(__bf16)f0.y; v[2]=(__bf16)f0.z; v[3]=(__bf16)f0.w;
            v[4]=(__bf16)f1.x; v[5]=(__bf16)f1.y; v[6]=(__bf16)f1.z; v[7]=(__bf16)f1.w;
        } else {
            v = *(const bf16x8*)(aggrB + (long)(n0 + nn) * C + (seg & 15) * 8);
        }
        *(bf16x8*)(&ldsF[swz8(nn, seg * 8)]) = v;
    }
    __syncthreads();

    f32x4 au = {0.f,0.f,0.f,0.f}, ar = {0.f,0.f,0.f,0.f};
    #pragma unroll
    for (int ks = 0; ks < 8; ++ks) {
        const bf16x8 b = *(const bf16x8*)(&ldsF[swz8(nr, ks * 32 + q * 8)]);
        au = __builtin_amdgcn_mfma_f32_16x16x32_bf16(aU[ks], b, au, 0, 0, 0);
    }
    #pragma unroll
    for (int ks = 0; ks < 4; ++ks) {
        const bf16x8 b = *(const bf16x8*)(&ldsF[swz8(nr, ks * 32 + q * 8)]);
        ar = __builtin_amdgcn_mfma_f32_16x16x32_bf16(aR[ks], b, ar, 0, 0, 0);
    }

    const int node = n0 + nr;
    float* dst = out + (long)node * C + chbase + q * 4;
    #pragma unroll
    for (int r = 0; r < 4; ++r)
        dst[r] = ar[r] + fmaxf(au[r] + bu[r], 0.f);
}

extern "C" void kernel_launch(void* const* d_in, const int* in_sizes, int n_in,
                              void* d_out, int out_size, void* d_ws, size_t ws_size,
                              hipStream_t stream) {
    const float* embed = (const float*)d_in[0];
    const float* pos   = (const float*)d_in[1];
    const float* Wres  = (const float*)d_in[2];
    const float* Wmsg  = (const float*)d_in[3];
    const float* bmsg  = (const float*)d_in[4];
    const float* Wupd  = (const float*)d_in[5];
    const float* bupd  = (const float*)d_in[6];
    const int*   eidx  = (const int*)d_in[7];
    float* out = (float*)d_out;

    char* ws = (char*)d_ws;
    int*            gcur  = (int*)(ws + WS_GCUR);
    unsigned*       rec   = (unsigned*)(ws + WS_REC);
    __bf16*         HdstB = (__bf16*)(ws + WS_HDST);
    unsigned char*  Hsrc8 = (unsigned char*)(ws + WS_HSRC8);
    __bf16*         aggrB = (__bf16*)(ws + WS_AGGR);

    hipMemsetAsync(gcur, 0, NB * sizeof(int), stream);
    fused_pp_kernel<<<PART_BLOCKS + PRE_BLOCKS, 512, 0, stream>>>(
        embed, Wmsg, bmsg, Hsrc8, HdstB, eidx, gcur, rec);
    aggr_kernel<<<N_NODES / 4, 256, 0, stream>>>(
        Hsrc8, HdstB, pos, Wmsg, gcur, rec, aggrB);
    node_upd_kernel<<<NTILES, 512, 0, stream>>>(
        embed, aggrB, Wres, Wupd, bupd, out);
}

// Round 12
// 118.454 us; speedup vs baseline: 1.1466x; 1.1466x over previous
//
#include <hip/hip_runtime.h>
#include <hip/hip_bf16.h>

#define N_NODES 50000
#define N_EDGES 640000
#define C 128            // IN_C == HID
#define NB 196           // dst buckets of 256 nodes (50000 <= 196*256)
#define BCAP 4096        // fixed edge capacity per bucket (mean 3277, +14 sigma)
#define NTILES (N_NODES / 16)                               // 3125
#define PART_BLOCKS 625  // partition blocks in fused_pp
#define PRE_BLOCKS 1024  // precomp blocks in fused_pp

typedef __bf16 bf16x8 __attribute__((ext_vector_type(8)));
typedef __bf16 bf16x4 __attribute__((ext_vector_type(4)));
typedef float  f32x4  __attribute__((ext_vector_type(4)));
typedef float  f32x2  __attribute__((ext_vector_type(2)));
typedef unsigned int u32x4 __attribute__((ext_vector_type(4)));

// ---- d_ws layout (byte offsets) ----
#define WS_GCUR  0          // NB ints (bucket cursors; zeroed by memset)
#define WS_OFFS  1024       // N ints (per-node edge range start)
#define WS_OFFE  201024     // N ints (per-node edge range end)
#define WS_SRCS  401024     // NB*BCAP ints (src ids, bucketed)
#define WS_REC   3612288    // NB*BCAP u32 packed records (src | dstLocal<<16)
#define WS_HDST  6823552    // N*C bf16 (Hdst + bias)
#define WS_HSRC8 19623552   // N*C fp8 e4m3 (6.4 MB)
#define WS_AGGR  26023552   // N*C bf16 (aggregation result)
// total ~38.8 MB

// XOR-swizzle for [16][128]-short LDS tiles (2-way residual conflict = free).
__device__ __forceinline__ int swzS(int row, int soff) {
    return row * 128 + (soff ^ ((row & 7) << 3));
}
// [16][256]-short variant (node-update staging)
__device__ __forceinline__ int swz8(int row, int soff) {
    return row * 256 + (soff ^ ((row & 7) << 3));
}

// ---------------------------------------------------------------------------
// fused_pp: blocks [0,625) partition edges into bucket slots;
//           blocks [625,1649) precompute Hsrc (fp8) / Hdst (bf16).
// The two phases touch disjoint data — one dispatch overlaps them.
// ---------------------------------------------------------------------------
__global__ __launch_bounds__(512) void fused_pp_kernel(
    const float* __restrict__ embed, const float* __restrict__ Wmsg,
    const float* __restrict__ bmsg,  unsigned char* __restrict__ Hsrc8,
    __bf16* __restrict__ Hdst, const int* __restrict__ eidx,
    int* __restrict__ gcur, unsigned* __restrict__ rec)
{
    __shared__ int   cnt[NB];
    __shared__ int   base[NB];
    __shared__ short lds[16 * 128];

    if (blockIdx.x < PART_BLOCKS) {
        // ---- partition phase: 1024 edges/block, LDS counters ----
        const int t = threadIdx.x;
        if (t < NB) cnt[t] = 0;
        __syncthreads();
        const int e0 = blockIdx.x * 1024;
        int lrank[2], bb[2];
        unsigned prec[2];
        #pragma unroll
        for (int k = 0; k < 2; ++k) {
            const int e = e0 + k * 512 + t;
            const int r = eidx[e], c = eidx[N_EDGES + e];
            bb[k]   = c >> 8;
            prec[k] = (unsigned)r | ((unsigned)(c & 255) << 16);
            lrank[k] = atomicAdd(&cnt[bb[k]], 1);
        }
        __syncthreads();
        if (t < NB) base[t] = t * BCAP + atomicAdd(&gcur[t], cnt[t]);
        __syncthreads();
        #pragma unroll
        for (int k = 0; k < 2; ++k)
            rec[base[bb[k]] + lrank[k]] = prec[k];
        return;
    }

    // ---- precomp phase ----
    const int t = threadIdx.x, lane = t & 63, wave = t >> 6;
    const int chbase = wave * 16, q = lane >> 4, nr = lane & 15;
    const int ch = chbase + nr;

    bf16x8 aS[4], aD[4];
    #pragma unroll
    for (int ks = 0; ks < 4; ++ks)
        #pragma unroll
        for (int i = 0; i < 8; ++i) {
            const int k = ks * 32 + q * 8 + i;
            aS[ks][i] = (__bf16)Wmsg[k * C + ch];
            aD[ks][i] = (__bf16)Wmsg[(128 + k) * C + ch];
        }
    float bias[4];
    #pragma unroll
    for (int r = 0; r < 4; ++r) bias[r] = bmsg[chbase + q * 4 + r];

    for (int nt = blockIdx.x - PART_BLOCKS; nt < NTILES; nt += PRE_BLOCKS) {
        const int n0 = nt * 16;
        {   // stage 16 nodes x 128 feats: f32 -> bf16 LDS
            const int row = t >> 5, seg = t & 31;
            const float4 f = *(const float4*)(embed + (long)(n0 + row) * C + seg * 4);
            bf16x4 v;
            v[0]=(__bf16)f.x; v[1]=(__bf16)f.y; v[2]=(__bf16)f.z; v[3]=(__bf16)f.w;
            *(bf16x4*)(&lds[swzS(row, seg * 4)]) = v;
        }
        __syncthreads();

        f32x4 hs = {0.f,0.f,0.f,0.f}, hd = {0.f,0.f,0.f,0.f};
        #pragma unroll
        for (int ks = 0; ks < 4; ++ks) {
            const bf16x8 b = *(const bf16x8*)(&lds[swzS(nr, ks * 32 + q * 8)]);
            hs = __builtin_amdgcn_mfma_f32_16x16x32_bf16(aS[ks], b, hs, 0, 0, 0);
            hd = __builtin_amdgcn_mfma_f32_16x16x32_bf16(aD[ks], b, hd, 0, 0, 0);
        }
        __syncthreads();

        const int node = n0 + nr;            // D: col=node, row(q*4+r)=ch
        int w8 = 0;
        w8 = __builtin_amdgcn_cvt_pk_fp8_f32(hs[0], hs[1], w8, false);
        w8 = __builtin_amdgcn_cvt_pk_fp8_f32(hs[2], hs[3], w8, true);
        *(unsigned*)(Hsrc8 + (long)node * C + chbase + q * 4) = (unsigned)w8;
        bf16x4 vd;
        #pragma unroll
        for (int r = 0; r < 4; ++r) vd[r] = (__bf16)(hd[r] + bias[r]);
        *(bf16x4*)(Hdst + (long)node * C + chbase + q * 4) = vd;
    }
}

// ---------------------------------------------------------------------------
// bucket_csr: one block per bucket. LDS deg-count over its 256 nodes -> scan
// -> offS/offE; LDS-cursor scatter of src ids into the bucket's srcS slot.
// ---------------------------------------------------------------------------
__global__ __launch_bounds__(256) void bucket_csr_kernel(
    const unsigned* __restrict__ rec, const int* __restrict__ gcur,
    int* __restrict__ offS, int* __restrict__ offE, int* __restrict__ srcS)
{
    __shared__ int deg[256];
    __shared__ int cur[256];
    __shared__ int lds[256];
    const int t = threadIdx.x, b = blockIdx.x;
    const int r0 = b * BCAP, r1 = r0 + gcur[b], n0 = b << 8;
    deg[t] = 0;
    __syncthreads();
    for (int i = r0 + t; i < r1; i += 256)
        atomicAdd(&deg[rec[i] >> 16], 1);
    __syncthreads();
    const int v = deg[t];
    lds[t] = v;
    __syncthreads();
    for (int s = 1; s < 256; s <<= 1) {
        const int u = (t >= s) ? lds[t - s] : 0;
        __syncthreads();
        lds[t] += u;
        __syncthreads();
    }
    const int excl = r0 + lds[t] - v;
    cur[t] = excl;
    if (n0 + t < N_NODES) { offS[n0 + t] = excl; offE[n0 + t] = excl + v; }
    __syncthreads();
    for (int i = r0 + t; i < r1; i += 256) {
        const unsigned rc = rec[i];
        const int p = atomicAdd(&cur[rc >> 16], 1);
        srcS[p] = (int)(rc & 0xFFFFu);
    }
}

// ---------------------------------------------------------------------------
// Aggregate: ONE NODE PER WAVE (grid*4 == N_NODES), 4 groups x 16 lanes
// (8 ch/lane), depth-2 pipeline (8 edges/iter in flight). Hsrc gathered as
// fp8 e4m3 (8B/lane/edge) and decoded with v_cvt_pk_f32_fp8. No LDS/barriers/
// atomics. Output aggr as bf16 to ws.
// ---------------------------------------------------------------------------
__global__ __launch_bounds__(256) void aggr_kernel(
    const unsigned char* __restrict__ Hsrc8, const __bf16* __restrict__ Hdst,
    const float*  __restrict__ pos,  const float* __restrict__ Wmsg,
    const int*    __restrict__ offS, const int*   __restrict__ offE,
    const int*    __restrict__ srcS, __bf16* __restrict__ aggrB)
{
    const int lane = threadIdx.x & 63;
    const int wv   = threadIdx.x >> 6;
    const int g    = lane >> 4;          // edge sub-group 0..3
    const int c8   = (lane & 15) * 8;    // channel base (8 ch/lane)

    float w2[8], hd[8], acc[8];
    *(f32x4*)&w2[0] = *(const f32x4*)(Wmsg + 256 * C + c8);
    *(f32x4*)&w2[4] = *(const f32x4*)(Wmsg + 256 * C + c8 + 4);

    const int n = blockIdx.x * 4 + wv;   // 12500*4 == 50000 exactly
    const int o0 = offS[n], o1 = offE[n];
    {   // unpack Hdst row slice (bf16 -> f32)
        const u32x4 hdb = *(const u32x4*)(Hdst + (long)n * C + c8);
        #pragma unroll
        for (int k = 0; k < 4; ++k) {
            hd[2*k]   = __uint_as_float(hdb[k] << 16);
            hd[2*k+1] = __uint_as_float(hdb[k] & 0xffff0000u);
        }
    }
    const float px = pos[n * 3], py = pos[n * 3 + 1], pz = pos[n * 3 + 2];
    #pragma unroll
    for (int j = 0; j < 8; ++j) acc[j] = 0.f;

    if (o1 > o0) {
        const int last = o1 - 1;
        int s0 = srcS[min(o0 + g,     last)];
        int s1 = srcS[min(o0 + 4 + g, last)];
        for (int e = o0; e < o1; e += 8) {
            // issue both halves' gathers, then prefetch next ids
            const float qx0 = pos[s0*3], qy0 = pos[s0*3+1], qz0 = pos[s0*3+2];
            const uint2 hu0 = *(const uint2*)(Hsrc8 + (long)s0 * C + c8);
            const float qx1 = pos[s1*3], qy1 = pos[s1*3+1], qz1 = pos[s1*3+2];
            const uint2 hu1 = *(const uint2*)(Hsrc8 + (long)s1 * C + c8);
            const int sn0 = srcS[min(e + 8  + g, last)];
            const int sn1 = srcS[min(e + 12 + g, last)];

            {   // half 0: edge e+g
                const float dx = qx0 - px, dy = qy0 - py, dz = qz0 - pz;
                const float d  = dx * dx + dy * dy + dz * dz;
                const bool valid = (e + g) < o1;
                const f32x2 p0 = __builtin_amdgcn_cvt_pk_f32_fp8((int)hu0.x, false);
                const f32x2 p1 = __builtin_amdgcn_cvt_pk_f32_fp8((int)hu0.x, true);
                const f32x2 p2 = __builtin_amdgcn_cvt_pk_f32_fp8((int)hu0.y, false);
                const f32x2 p3 = __builtin_amdgcn_cvt_pk_f32_fp8((int)hu0.y, true);
                const float hs[8] = {p0[0],p0[1],p1[0],p1[1],p2[0],p2[1],p3[0],p3[1]};
                #pragma unroll
                for (int j = 0; j < 8; ++j) {
                    const float v = fmaxf(hs[j] + hd[j] + d * w2[j], 0.f);
                    acc[j] += valid ? v : 0.f;
                }
            }
            {   // half 1: edge e+4+g
                const float dx = qx1 - px, dy = qy1 - py, dz = qz1 - pz;
                const float d  = dx * dx + dy * dy + dz * dz;
                const bool valid = (e + 4 + g) < o1;
                const f32x2 p0 = __builtin_amdgcn_cvt_pk_f32_fp8((int)hu1.x, false);
                const f32x2 p1 = __builtin_amdgcn_cvt_pk_f32_fp8((int)hu1.x, true);
                const f32x2 p2 = __builtin_amdgcn_cvt_pk_f32_fp8((int)hu1.y, false);
                const f32x2 p3 = __builtin_amdgcn_cvt_pk_f32_fp8((int)hu1.y, true);
                const float hs[8] = {p0[0],p0[1],p1[0],p1[1],p2[0],p2[1],p3[0],p3[1]};
                #pragma unroll
                for (int j = 0; j < 8; ++j) {
                    const float v = fmaxf(hs[j] + hd[j] + d * w2[j], 0.f);
                    acc[j] += valid ? v : 0.f;
                }
            }
            s0 = sn0; s1 = sn1;
        }
    }
    #pragma unroll
    for (int j = 0; j < 8; ++j) {        // combine the 4 edge groups
        acc[j] += __shfl_xor(acc[j], 16);
        acc[j] += __shfl_xor(acc[j], 32);
    }
    if (lane < 16) {
        bf16x8 v;
        #pragma unroll
        for (int j = 0; j < 8; ++j) v[j] = (__bf16)acc[j];
        *(bf16x8*)(aggrB + (long)n * C + c8) = v;
    }
}

// ---------------------------------------------------------------------------
// Node update: out = embed @ W_res + relu([embed, aggr] @ W_upd + b_upd)
// One 16-node tile per block (grid = NTILES).
// ---------------------------------------------------------------------------
__global__ __launch_bounds__(512) void node_upd_kernel(
    const float* __restrict__ embed, const __bf16* __restrict__ aggrB,
    const float* __restrict__ Wres,  const float* __restrict__ Wupd,
    const float* __restrict__ bupd,  float* __restrict__ out)
{
    __shared__ short ldsF[16 * 256];

    const int t = threadIdx.x, lane = t & 63, wave = t >> 6;
    const int chbase = wave * 16, q = lane >> 4, nr = lane & 15;

    bf16x8 aU[8], aR[4];
    {
        const int ch = chbase + nr;
        #pragma unroll
        for (int ks = 0; ks < 8; ++ks)
            #pragma unroll
            for (int i = 0; i < 8; ++i)
                aU[ks][i] = (__bf16)Wupd[(ks*32 + q*8 + i) * C + ch];
        #pragma unroll
        for (int ks = 0; ks < 4; ++ks)
            #pragma unroll
            for (int i = 0; i < 8; ++i)
                aR[ks][i] = (__bf16)Wres[(ks*32 + q*8 + i) * C + ch];
    }
    float bu[4];
    #pragma unroll
    for (int r = 0; r < 4; ++r) bu[r] = bupd[chbase + q*4 + r];

    const int n0 = blockIdx.x * 16;
    {   // stage [embed(f32->bf16) | aggr(bf16 copy)] for 16 nodes
        const int nn = t >> 5, seg = t & 31;
        bf16x8 v;
        if (seg < 16) {
            const float* src = embed + (long)(n0 + nn) * C + seg * 8;
            const float4 f0 = *(const float4*)src;
            const float4 f1 = *(const float4*)(src + 4);
            v[0]=(__bf16)f0.x; v[1]=(__bf16)f0.y; v[2]=(__bf16)f0.z; v[3]=(__bf16)f0.w;
            v[4]=(__bf16)f1.x; v[5]=(__bf16)f1.y; v[6]=(__bf16)f1.z; v[7]=(__bf16)f1.w;
        } else {
            v = *(const bf16x8*)(aggrB + (long)(n0 + nn) * C + (seg & 15) * 8);
        }
        *(bf16x8*)(&ldsF[swz8(nn, seg * 8)]) = v;
    }
    __syncthreads();

    f32x4 au = {0.f,0.f,0.f,0.f}, ar = {0.f,0.f,0.f,0.f};
    #pragma unroll
    for (int ks = 0; ks < 8; ++ks) {
        const bf16x8 b = *(const bf16x8*)(&ldsF[swz8(nr, ks * 32 + q * 8)]);
        au = __builtin_amdgcn_mfma_f32_16x16x32_bf16(aU[ks], b, au, 0, 0, 0);
    }
    #pragma unroll
    for (int ks = 0; ks < 4; ++ks) {
        const bf16x8 b = *(const bf16x8*)(&ldsF[swz8(nr, ks * 32 + q * 8)]);
        ar = __builtin_amdgcn_mfma_f32_16x16x32_bf16(aR[ks], b, ar, 0, 0, 0);
    }

    const int node = n0 + nr;
    float* dst = out + (long)node * C + chbase + q * 4;
    #pragma unroll
    for (int r = 0; r < 4; ++r)
        dst[r] = ar[r] + fmaxf(au[r] + bu[r], 0.f);
}

extern "C" void kernel_launch(void* const* d_in, const int* in_sizes, int n_in,
                              void* d_out, int out_size, void* d_ws, size_t ws_size,
                              hipStream_t stream) {
    const float* embed = (const float*)d_in[0];
    const float* pos   = (const float*)d_in[1];
    const float* Wres  = (const float*)d_in[2];
    const float* Wmsg  = (const float*)d_in[3];
    const float* bmsg  = (const float*)d_in[4];
    const float* Wupd  = (const float*)d_in[5];
    const float* bupd  = (const float*)d_in[6];
    const int*   eidx  = (const int*)d_in[7];
    float* out = (float*)d_out;

    char* ws = (char*)d_ws;
    int*            gcur  = (int*)(ws + WS_GCUR);
    int*            offS  = (int*)(ws + WS_OFFS);
    int*            offE  = (int*)(ws + WS_OFFE);
    int*            srcS  = (int*)(ws + WS_SRCS);
    unsigned*       rec   = (unsigned*)(ws + WS_REC);
    __bf16*         HdstB = (__bf16*)(ws + WS_HDST);
    unsigned char*  Hsrc8 = (unsigned char*)(ws + WS_HSRC8);
    __bf16*         aggrB = (__bf16*)(ws + WS_AGGR);

    hipMemsetAsync(gcur, 0, NB * sizeof(int), stream);
    fused_pp_kernel<<<PART_BLOCKS + PRE_BLOCKS, 512, 0, stream>>>(
        embed, Wmsg, bmsg, Hsrc8, HdstB, eidx, gcur, rec);
    bucket_csr_kernel<<<NB, 256, 0, stream>>>(rec, gcur, offS, offE, srcS);
    aggr_kernel<<<N_NODES / 4, 256, 0, stream>>>(
        Hsrc8, HdstB, pos, Wmsg, offS, offE, srcS, aggrB);
    node_upd_kernel<<<NTILES, 512, 0, stream>>>(
        embed, aggrB, Wres, Wupd, bupd, out);
}

// Round 13
// 100.562 us; speedup vs baseline: 1.3506x; 1.1779x over previous
//
#include <hip/hip_runtime.h>
#include <hip/hip_bf16.h>

#define N_NODES 50000
#define N_EDGES 640000
#define C 128            // IN_C == HID
#define NB 196           // dst buckets of 256 nodes (50000 <= 196*256)
#define BCAP 4096        // fixed edge capacity per bucket (mean 3277, +14 sigma)
#define NTILES (N_NODES / 16)                               // 3125

typedef __bf16 bf16x8 __attribute__((ext_vector_type(8)));
typedef __bf16 bf16x4 __attribute__((ext_vector_type(4)));
typedef float  f32x4  __attribute__((ext_vector_type(4)));
typedef float  f32x2  __attribute__((ext_vector_type(2)));
typedef unsigned int u32x4 __attribute__((ext_vector_type(4)));

// ---- d_ws layout (byte offsets) ----
#define WS_GCUR  0          // NB ints (bucket cursors; zeroed by precomp blk0)
#define WS_OFFS  1024       // N ints (per-node edge range start)
#define WS_OFFE  201024     // N ints (per-node edge range end)
#define WS_SRCD  401024     // NB*BCAP int2 (src id, dist bits) = 6.4 MB
#define WS_REC   6823552    // NB*BCAP u32 packed records (src | dstLocal<<16)
#define WS_HDST  10034816   // N*C bf16 (Hdst + bias)
#define WS_HSRC8 22834816   // N*C fp8 e4m3 (6.4 MB)
#define WS_AGGR  29234816   // N*C bf16 (aggregation result)
// total ~42 MB

// XOR-swizzle for [16][128]-short LDS tiles (2-way residual conflict = free).
__device__ __forceinline__ int swzS(int row, int soff) {
    return row * 128 + (soff ^ ((row & 7) << 3));
}
// [16][256]-short variant (node-update staging)
__device__ __forceinline__ int swz8(int row, int soff) {
    return row * 256 + (soff ^ ((row & 7) << 3));
}

// ---------------------------------------------------------------------------
// Precompute Hsrc = embed @ Wmsg[0:128]          (fp8 e4m3, ws)
//            Hdst = embed @ Wmsg[128:256] + b    (bf16, ws)
// Runs FIRST; block 0 also zeroes gcur (stream order covers the dependency).
// ---------------------------------------------------------------------------
__global__ __launch_bounds__(512) void precomp_kernel(
    const float* __restrict__ embed, const float* __restrict__ Wmsg,
    const float* __restrict__ bmsg,  unsigned char* __restrict__ Hsrc8,
    __bf16* __restrict__ Hdst, int* __restrict__ gcur)
{
    __shared__ short lds[16 * 128];

    const int t = threadIdx.x, lane = t & 63, wave = t >> 6;
    const int chbase = wave * 16, q = lane >> 4, nr = lane & 15;
    const int ch = chbase + nr;

    if (blockIdx.x == 0 && t < NB) gcur[t] = 0;

    bf16x8 aS[4], aD[4];
    #pragma unroll
    for (int ks = 0; ks < 4; ++ks)
        #pragma unroll
        for (int i = 0; i < 8; ++i) {
            const int k = ks * 32 + q * 8 + i;
            aS[ks][i] = (__bf16)Wmsg[k * C + ch];
            aD[ks][i] = (__bf16)Wmsg[(128 + k) * C + ch];
        }
    float bias[4];
    #pragma unroll
    for (int r = 0; r < 4; ++r) bias[r] = bmsg[chbase + q * 4 + r];

    for (int nt = blockIdx.x; nt < NTILES; nt += gridDim.x) {
        const int n0 = nt * 16;
        {   // stage 16 nodes x 128 feats: f32 -> bf16 LDS
            const int row = t >> 5, seg = t & 31;
            const float4 f = *(const float4*)(embed + (long)(n0 + row) * C + seg * 4);
            bf16x4 v;
            v[0]=(__bf16)f.x; v[1]=(__bf16)f.y; v[2]=(__bf16)f.z; v[3]=(__bf16)f.w;
            *(bf16x4*)(&lds[swzS(row, seg * 4)]) = v;
        }
        __syncthreads();

        f32x4 hs = {0.f,0.f,0.f,0.f}, hd = {0.f,0.f,0.f,0.f};
        #pragma unroll
        for (int ks = 0; ks < 4; ++ks) {
            const bf16x8 b = *(const bf16x8*)(&lds[swzS(nr, ks * 32 + q * 8)]);
            hs = __builtin_amdgcn_mfma_f32_16x16x32_bf16(aS[ks], b, hs, 0, 0, 0);
            hd = __builtin_amdgcn_mfma_f32_16x16x32_bf16(aD[ks], b, hd, 0, 0, 0);
        }
        __syncthreads();

        const int node = n0 + nr;            // D: col=node, row(q*4+r)=ch
        int w8 = 0;
        w8 = __builtin_amdgcn_cvt_pk_fp8_f32(hs[0], hs[1], w8, false);
        w8 = __builtin_amdgcn_cvt_pk_fp8_f32(hs[2], hs[3], w8, true);
        *(unsigned*)(Hsrc8 + (long)node * C + chbase + q * 4) = (unsigned)w8;
        bf16x4 vd;
        #pragma unroll
        for (int r = 0; r < 4; ++r) vd[r] = (__bf16)(hd[r] + bias[r]);
        *(bf16x4*)(Hdst + (long)node * C + chbase + q * 4) = vd;
    }
}

// ---------------------------------------------------------------------------
// partition: bin 1024 edges/block by dst>>8 via LDS counters; reserve a range
// in the bucket's FIXED slot [b*BCAP, (b+1)*BCAP) with one global atomic per
// bucket per block; write packed 4B records (src | dstLocal<<16).
// ---------------------------------------------------------------------------
__global__ __launch_bounds__(256) void partition_kernel(
    const int* __restrict__ eidx, int* __restrict__ gcur,
    unsigned* __restrict__ rec)
{
    __shared__ int cnt[NB];
    __shared__ int base[NB];
    const int t = threadIdx.x;
    if (t < NB) cnt[t] = 0;
    __syncthreads();
    const int e0 = blockIdx.x * 1024;
    int lrank[4], bb[4];
    unsigned prec[4];
    #pragma unroll
    for (int k = 0; k < 4; ++k) {
        const int e = e0 + k * 256 + t;
        const int r = eidx[e], c = eidx[N_EDGES + e];
        bb[k]   = c >> 8;
        prec[k] = (unsigned)r | ((unsigned)(c & 255) << 16);
        lrank[k] = atomicAdd(&cnt[bb[k]], 1);
    }
    __syncthreads();
    if (t < NB) base[t] = t * BCAP + atomicAdd(&gcur[t], cnt[t]);
    __syncthreads();
    #pragma unroll
    for (int k = 0; k < 4; ++k)
        rec[base[bb[k]] + lrank[k]] = prec[k];
}

// ---------------------------------------------------------------------------
// bucket_csr: one block per bucket. LDS deg-count over its 256 nodes -> scan
// -> offS/offE; then scatter (src, dist) pairs into the bucket's srcD slot.
// dist precomputed here (dst positions staged in LDS) so aggr's critical
// gather chain drops the random pos[s] loads entirely.
// ---------------------------------------------------------------------------
__global__ __launch_bounds__(256) void bucket_csr_kernel(
    const unsigned* __restrict__ rec, const int* __restrict__ gcur,
    const float* __restrict__ pos, int* __restrict__ offS,
    int* __restrict__ offE, int2* __restrict__ srcD)
{
    __shared__ int   deg[256];
    __shared__ int   cur[256];
    __shared__ int   lds[256];
    __shared__ float dpx[256], dpy[256], dpz[256];
    const int t = threadIdx.x, b = blockIdx.x;
    const int r0 = b * BCAP, r1 = r0 + gcur[b], n0 = b << 8;
    deg[t] = 0;
    {   // stage this bucket's 256 dst positions
        const int nn = n0 + t;
        const int cl = min(nn, N_NODES - 1);
        dpx[t] = pos[cl * 3]; dpy[t] = pos[cl * 3 + 1]; dpz[t] = pos[cl * 3 + 2];
    }
    __syncthreads();
    for (int i = r0 + t; i < r1; i += 256)
        atomicAdd(&deg[rec[i] >> 16], 1);
    __syncthreads();
    const int v = deg[t];
    lds[t] = v;
    __syncthreads();
    for (int s = 1; s < 256; s <<= 1) {
        const int u = (t >= s) ? lds[t - s] : 0;
        __syncthreads();
        lds[t] += u;
        __syncthreads();
    }
    const int excl = r0 + lds[t] - v;
    cur[t] = excl;
    if (n0 + t < N_NODES) { offS[n0 + t] = excl; offE[n0 + t] = excl + v; }
    __syncthreads();
    for (int i = r0 + t; i < r1; i += 256) {
        const unsigned rc = rec[i];
        const int dl  = (int)(rc >> 16);
        const int src = (int)(rc & 0xFFFFu);
        const float dx = pos[src * 3]     - dpx[dl];
        const float dy = pos[src * 3 + 1] - dpy[dl];
        const float dz = pos[src * 3 + 2] - dpz[dl];
        const float d  = dx * dx + dy * dy + dz * dz;
        const int p = atomicAdd(&cur[dl], 1);
        srcD[p] = make_int2(src, __float_as_int(d));
    }
}

// ---------------------------------------------------------------------------
// Aggregate: ONE NODE PER WAVE (grid*4 == N_NODES), 4 groups x 16 lanes
// (8 ch/lane), depth-2 pipeline (8 edges/iter in flight). Per edge: one 8B
// (src,dist) stream read + one fp8 row gather — no pos chain. No LDS/
// barriers/atomics. Output aggr as bf16 to ws.
// ---------------------------------------------------------------------------
__global__ __launch_bounds__(256) void aggr_kernel(
    const unsigned char* __restrict__ Hsrc8, const __bf16* __restrict__ Hdst,
    const float*  __restrict__ Wmsg,
    const int*    __restrict__ offS, const int*   __restrict__ offE,
    const int2*   __restrict__ srcD, __bf16* __restrict__ aggrB)
{
    const int lane = threadIdx.x & 63;
    const int wv   = threadIdx.x >> 6;
    const int g    = lane >> 4;          // edge sub-group 0..3
    const int c8   = (lane & 15) * 8;    // channel base (8 ch/lane)

    float w2[8], hd[8], acc[8];
    *(f32x4*)&w2[0] = *(const f32x4*)(Wmsg + 256 * C + c8);
    *(f32x4*)&w2[4] = *(const f32x4*)(Wmsg + 256 * C + c8 + 4);

    const int n = blockIdx.x * 4 + wv;   // 12500*4 == 50000 exactly
    const int o0 = offS[n], o1 = offE[n];
    {   // unpack Hdst row slice (bf16 -> f32)
        const u32x4 hdb = *(const u32x4*)(Hdst + (long)n * C + c8);
        #pragma unroll
        for (int k = 0; k < 4; ++k) {
            hd[2*k]   = __uint_as_float(hdb[k] << 16);
            hd[2*k+1] = __uint_as_float(hdb[k] & 0xffff0000u);
        }
    }
    #pragma unroll
    for (int j = 0; j < 8; ++j) acc[j] = 0.f;

    if (o1 > o0) {
        const int last = o1 - 1;
        int2 sd0 = srcD[min(o0 + g,     last)];
        int2 sd1 = srcD[min(o0 + 4 + g, last)];
        for (int e = o0; e < o1; e += 8) {
            // issue both halves' gathers, then prefetch next (src,dist)
            const uint2 hu0 = *(const uint2*)(Hsrc8 + (long)sd0.x * C + c8);
            const uint2 hu1 = *(const uint2*)(Hsrc8 + (long)sd1.x * C + c8);
            const float d0 = __int_as_float(sd0.y);
            const float d1 = __int_as_float(sd1.y);
            const int2 sn0 = srcD[min(e + 8  + g, last)];
            const int2 sn1 = srcD[min(e + 12 + g, last)];

            {   // half 0: edge e+g
                const bool valid = (e + g) < o1;
                const f32x2 p0 = __builtin_amdgcn_cvt_pk_f32_fp8((int)hu0.x, false);
                const f32x2 p1 = __builtin_amdgcn_cvt_pk_f32_fp8((int)hu0.x, true);
                const f32x2 p2 = __builtin_amdgcn_cvt_pk_f32_fp8((int)hu0.y, false);
                const f32x2 p3 = __builtin_amdgcn_cvt_pk_f32_fp8((int)hu0.y, true);
                const float hs[8] = {p0[0],p0[1],p1[0],p1[1],p2[0],p2[1],p3[0],p3[1]};
                #pragma unroll
                for (int j = 0; j < 8; ++j) {
                    const float v = fmaxf(hs[j] + hd[j] + d0 * w2[j], 0.f);
                    acc[j] += valid ? v : 0.f;
                }
            }
            {   // half 1: edge e+4+g
                const bool valid = (e + 4 + g) < o1;
                const f32x2 p0 = __builtin_amdgcn_cvt_pk_f32_fp8((int)hu1.x, false);
                const f32x2 p1 = __builtin_amdgcn_cvt_pk_f32_fp8((int)hu1.x, true);
                const f32x2 p2 = __builtin_amdgcn_cvt_pk_f32_fp8((int)hu1.y, false);
                const f32x2 p3 = __builtin_amdgcn_cvt_pk_f32_fp8((int)hu1.y, true);
                const float hs[8] = {p0[0],p0[1],p1[0],p1[1],p2[0],p2[1],p3[0],p3[1]};
                #pragma unroll
                for (int j = 0; j < 8; ++j) {
                    const float v = fmaxf(hs[j] + hd[j] + d1 * w2[j], 0.f);
                    acc[j] += valid ? v : 0.f;
                }
            }
            sd0 = sn0; sd1 = sn1;
        }
    }
    #pragma unroll
    for (int j = 0; j < 8; ++j) {        // combine the 4 edge groups
        acc[j] += __shfl_xor(acc[j], 16);
        acc[j] += __shfl_xor(acc[j], 32);
    }
    if (lane < 16) {
        bf16x8 v;
        #pragma unroll
        for (int j = 0; j < 8; ++j) v[j] = (__bf16)acc[j];
        *(bf16x8*)(aggrB + (long)n * C + c8) = v;
    }
}

// ---------------------------------------------------------------------------
// Node update: out = embed @ W_res + relu([embed, aggr] @ W_upd + b_upd)
// Grid 1024, ~3 tiles/block (amortizes the 96-value weight fragment load).
// ---------------------------------------------------------------------------
__global__ __launch_bounds__(512) void node_upd_kernel(
    const float* __restrict__ embed, const __bf16* __restrict__ aggrB,
    const float* __restrict__ Wres,  const float* __restrict__ Wupd,
    const float* __restrict__ bupd,  float* __restrict__ out)
{
    __shared__ short ldsF[16 * 256];

    const int t = threadIdx.x, lane = t & 63, wave = t >> 6;
    const int chbase = wave * 16, q = lane >> 4, nr = lane & 15;

    bf16x8 aU[8], aR[4];
    {
        const int ch = chbase + nr;
        #pragma unroll
        for (int ks = 0; ks < 8; ++ks)
            #pragma unroll
            for (int i = 0; i < 8; ++i)
                aU[ks][i] = (__bf16)Wupd[(ks*32 + q*8 + i) * C + ch];
        #pragma unroll
        for (int ks = 0; ks < 4; ++ks)
            #pragma unroll
            for (int i = 0; i < 8; ++i)
                aR[ks][i] = (__bf16)Wres[(ks*32 + q*8 + i) * C + ch];
    }
    float bu[4];
    #pragma unroll
    for (int r = 0; r < 4; ++r) bu[r] = bupd[chbase + q*4 + r];

    for (int nt = blockIdx.x; nt < NTILES; nt += gridDim.x) {
        const int n0 = nt * 16;
        {   // stage [embed(f32->bf16) | aggr(bf16 copy)] for 16 nodes
            const int nn = t >> 5, seg = t & 31;
            bf16x8 v;
            if (seg < 16) {
                const float* src = embed + (long)(n0 + nn) * C + seg * 8;
                const float4 f0 = *(const float4*)src;
                const float4 f1 = *(const float4*)(src + 4);
                v[0]=(__bf16)f0.x; v[1]=(__bf16)f0.y; v[2]=(__bf16)f0.z; v[3]=(__bf16)f0.w;
                v[4]=(__bf16)f1.x; v[5]=(__bf16)f1.y; v[6]=(__bf16)f1.z; v[7]=(__bf16)f1.w;
            } else {
                v = *(const bf16x8*)(aggrB + (long)(n0 + nn) * C + (seg & 15) * 8);
            }
            *(bf16x8*)(&ldsF[swz8(nn, seg * 8)]) = v;
        }
        __syncthreads();

        f32x4 au = {0.f,0.f,0.f,0.f}, ar = {0.f,0.f,0.f,0.f};
        #pragma unroll
        for (int ks = 0; ks < 8; ++ks) {
            const bf16x8 b = *(const bf16x8*)(&ldsF[swz8(nr, ks * 32 + q * 8)]);
            au = __builtin_amdgcn_mfma_f32_16x16x32_bf16(aU[ks], b, au, 0, 0, 0);
        }
        #pragma unroll
        for (int ks = 0; ks < 4; ++ks) {
            const bf16x8 b = *(const bf16x8*)(&ldsF[swz8(nr, ks * 32 + q * 8)]);
            ar = __builtin_amdgcn_mfma_f32_16x16x32_bf16(aR[ks], b, ar, 0, 0, 0);
        }
        __syncthreads();

        const int node = n0 + nr;
        float* dst = out + (long)node * C + chbase + q * 4;
        #pragma unroll
        for (int r = 0; r < 4; ++r)
            dst[r] = ar[r] + fmaxf(au[r] + bu[r], 0.f);
    }
}

extern "C" void kernel_launch(void* const* d_in, const int* in_sizes, int n_in,
                              void* d_out, int out_size, void* d_ws, size_t ws_size,
                              hipStream_t stream) {
    const float* embed = (const float*)d_in[0];
    const float* pos   = (const float*)d_in[1];
    const float* Wres  = (const float*)d_in[2];
    const float* Wmsg  = (const float*)d_in[3];
    const float* bmsg  = (const float*)d_in[4];
    const float* Wupd  = (const float*)d_in[5];
    const float* bupd  = (const float*)d_in[6];
    const int*   eidx  = (const int*)d_in[7];
    float* out = (float*)d_out;

    char* ws = (char*)d_ws;
    int*            gcur  = (int*)(ws + WS_GCUR);
    int*            offS  = (int*)(ws + WS_OFFS);
    int*            offE  = (int*)(ws + WS_OFFE);
    int2*           srcD  = (int2*)(ws + WS_SRCD);
    unsigned*       rec   = (unsigned*)(ws + WS_REC);
    __bf16*         HdstB = (__bf16*)(ws + WS_HDST);
    unsigned char*  Hsrc8 = (unsigned char*)(ws + WS_HSRC8);
    __bf16*         aggrB = (__bf16*)(ws + WS_AGGR);

    precomp_kernel<<<1024, 512, 0, stream>>>(embed, Wmsg, bmsg, Hsrc8, HdstB, gcur);
    partition_kernel<<<N_EDGES / 1024, 256, 0, stream>>>(eidx, gcur, rec);
    bucket_csr_kernel<<<NB, 256, 0, stream>>>(rec, gcur, pos, offS, offE, srcD);
    aggr_kernel<<<N_NODES / 4, 256, 0, stream>>>(Hsrc8, HdstB, Wmsg, offS, offE, srcD, aggrB);
    node_upd_kernel<<<1024, 512, 0, stream>>>(embed, aggrB, Wres, Wupd, bupd, out);
}

// Round 14
// 98.277 us; speedup vs baseline: 1.3820x; 1.0233x over previous
//
#include <hip/hip_runtime.h>
#include <hip/hip_bf16.h>

#define N_NODES 50000
#define N_EDGES 640000
#define C 128            // IN_C == HID
#define NB 196           // dst buckets of 256 nodes (50000 <= 196*256)
#define BCAP 5120        // per-bucket slot (raw mean 3277, padded mean 4199, +15 sigma)
#define NTILES (N_NODES / 16)                               // 3125

typedef __bf16 bf16x8 __attribute__((ext_vector_type(8)));
typedef __bf16 bf16x4 __attribute__((ext_vector_type(4)));
typedef float  f32x4  __attribute__((ext_vector_type(4)));
typedef float  f32x2  __attribute__((ext_vector_type(2)));
typedef unsigned int u32x4 __attribute__((ext_vector_type(4)));

// ---- d_ws layout (byte offsets) ----
#define WS_GCUR   0          // NB ints (bucket cursors; zeroed by precomp blk0)
#define WS_OFFS   1024       // N ints (padded range start)
#define WS_OFFE   201216     // N ints (padded range end)
#define WS_SRCD   401408     // NB*BCAP int2 + slack (src id, dist bits)
#define WS_REC    8429824    // NB*BCAP u32 packed records (src | dstLocal<<16)
#define WS_HDST   12443904   // N*C bf16 (Hdst + bias)
#define WS_HSRC8  25243904   // (N+1)*C fp8 e4m3 (row N = dummy, all 0xFE)
#define WS_EMBB   31644160   // N*C bf16 (embed, pre-converted)
#define WS_AGGR   44444160   // N*C bf16 (aggregation result)
// total ~57.2 MB

// XOR-swizzle for [16][128]-short LDS tiles (2-way residual conflict = free).
__device__ __forceinline__ int swzS(int row, int soff) {
    return row * 128 + (soff ^ ((row & 7) << 3));
}
// [16][256]-short variant (node-update staging)
__device__ __forceinline__ int swz8(int row, int soff) {
    return row * 256 + (soff ^ ((row & 7) << 3));
}

// ---------------------------------------------------------------------------
// Precompute Hsrc = embed @ Wmsg[0:128]          (fp8 e4m3, ws)
//            Hdst = embed @ Wmsg[128:256] + b    (bf16, ws)
//            embedB = bf16(embed)                (free: staging regs re-stored)
// Block 0 zeroes gcur and writes the dummy Hsrc8 row (0xFE = -448 fp8).
// ---------------------------------------------------------------------------
__global__ __launch_bounds__(512) void precomp_kernel(
    const float* __restrict__ embed, const float* __restrict__ Wmsg,
    const float* __restrict__ bmsg,  unsigned char* __restrict__ Hsrc8,
    __bf16* __restrict__ Hdst, __bf16* __restrict__ embedB,
    int* __restrict__ gcur)
{
    __shared__ short lds[16 * 128];

    const int t = threadIdx.x, lane = t & 63, wave = t >> 6;
    const int chbase = wave * 16, q = lane >> 4, nr = lane & 15;
    const int ch = chbase + nr;

    if (blockIdx.x == 0) {
        if (t < NB) gcur[t] = 0;
        if (t < 16)  // dummy row: relu(-448 + hd + 0) == 0 for any real hd
            *(unsigned long long*)(Hsrc8 + (long)N_NODES * C + t * 8) =
                0xFEFEFEFEFEFEFEFEULL;
    }

    bf16x8 aS[4], aD[4];
    #pragma unroll
    for (int ks = 0; ks < 4; ++ks)
        #pragma unroll
        for (int i = 0; i < 8; ++i) {
            const int k = ks * 32 + q * 8 + i;
            aS[ks][i] = (__bf16)Wmsg[k * C + ch];
            aD[ks][i] = (__bf16)Wmsg[(128 + k) * C + ch];
        }
    float bias[4];
    #pragma unroll
    for (int r = 0; r < 4; ++r) bias[r] = bmsg[chbase + q * 4 + r];

    for (int nt = blockIdx.x; nt < NTILES; nt += gridDim.x) {
        const int n0 = nt * 16;
        {   // stage 16 nodes x 128 feats: f32 -> bf16 LDS (+ store embedB copy)
            const int row = t >> 5, seg = t & 31;
            const float4 f = *(const float4*)(embed + (long)(n0 + row) * C + seg * 4);
            bf16x4 v;
            v[0]=(__bf16)f.x; v[1]=(__bf16)f.y; v[2]=(__bf16)f.z; v[3]=(__bf16)f.w;
            *(bf16x4*)(&lds[swzS(row, seg * 4)]) = v;
            *(bf16x4*)(embedB + (long)(n0 + row) * C + seg * 4) = v;
        }
        __syncthreads();

        f32x4 hs = {0.f,0.f,0.f,0.f}, hd = {0.f,0.f,0.f,0.f};
        #pragma unroll
        for (int ks = 0; ks < 4; ++ks) {
            const bf16x8 b = *(const bf16x8*)(&lds[swzS(nr, ks * 32 + q * 8)]);
            hs = __builtin_amdgcn_mfma_f32_16x16x32_bf16(aS[ks], b, hs, 0, 0, 0);
            hd = __builtin_amdgcn_mfma_f32_16x16x32_bf16(aD[ks], b, hd, 0, 0, 0);
        }
        __syncthreads();

        const int node = n0 + nr;            // D: col=node, row(q*4+r)=ch
        int w8 = 0;
        w8 = __builtin_amdgcn_cvt_pk_fp8_f32(hs[0], hs[1], w8, false);
        w8 = __builtin_amdgcn_cvt_pk_fp8_f32(hs[2], hs[3], w8, true);
        *(unsigned*)(Hsrc8 + (long)node * C + chbase + q * 4) = (unsigned)w8;
        bf16x4 vd;
        #pragma unroll
        for (int r = 0; r < 4; ++r) vd[r] = (__bf16)(hd[r] + bias[r]);
        *(bf16x4*)(Hdst + (long)node * C + chbase + q * 4) = vd;
    }
}

// ---------------------------------------------------------------------------
// partition: bin 1024 edges/block by dst>>8 via LDS counters; reserve a range
// in the bucket's FIXED slot [b*BCAP, (b+1)*BCAP) with one global atomic per
// bucket per block; write packed 4B records (src | dstLocal<<16).
// ---------------------------------------------------------------------------
__global__ __launch_bounds__(256) void partition_kernel(
    const int* __restrict__ eidx, int* __restrict__ gcur,
    unsigned* __restrict__ rec)
{
    __shared__ int cnt[NB];
    __shared__ int base[NB];
    const int t = threadIdx.x;
    if (t < NB) cnt[t] = 0;
    __syncthreads();
    const int e0 = blockIdx.x * 1024;
    int lrank[4], bb[4];
    unsigned prec[4];
    #pragma unroll
    for (int k = 0; k < 4; ++k) {
        const int e = e0 + k * 256 + t;
        const int r = eidx[e], c = eidx[N_EDGES + e];
        bb[k]   = c >> 8;
        prec[k] = (unsigned)r | ((unsigned)(c & 255) << 16);
        lrank[k] = atomicAdd(&cnt[bb[k]], 1);
    }
    __syncthreads();
    if (t < NB) base[t] = t * BCAP + atomicAdd(&gcur[t], cnt[t]);
    __syncthreads();
    #pragma unroll
    for (int k = 0; k < 4; ++k)
        rec[base[bb[k]] + lrank[k]] = prec[k];
}

// ---------------------------------------------------------------------------
// bucket_csr: one block per bucket. LDS deg-count -> scan of PADDED degrees
// (multiple of 8) -> offS/offE; scatter (src, dist) pairs; fill each node's
// tail [offS+deg, offS+pdeg) with dummy records (src=N_NODES, d=0).
// ---------------------------------------------------------------------------
__global__ __launch_bounds__(256) void bucket_csr_kernel(
    const unsigned* __restrict__ rec, const int* __restrict__ gcur,
    const float* __restrict__ pos, int* __restrict__ offS,
    int* __restrict__ offE, int2* __restrict__ srcD)
{
    __shared__ int   deg[256];
    __shared__ int   cur[256];
    __shared__ int   lds[256];
    __shared__ float dpx[256], dpy[256], dpz[256];
    const int t = threadIdx.x, b = blockIdx.x;
    const int r0 = b * BCAP, r1 = r0 + gcur[b], n0 = b << 8;
    deg[t] = 0;
    {   // stage this bucket's 256 dst positions
        const int nn = n0 + t;
        const int cl = min(nn, N_NODES - 1);
        dpx[t] = pos[cl * 3]; dpy[t] = pos[cl * 3 + 1]; dpz[t] = pos[cl * 3 + 2];
    }
    __syncthreads();
    for (int i = r0 + t; i < r1; i += 256)
        atomicAdd(&deg[rec[i] >> 16], 1);
    __syncthreads();
    const int v  = deg[t];
    const int pd = (v + 7) & ~7;          // pad to multiple of 8
    lds[t] = pd;
    __syncthreads();
    for (int s = 1; s < 256; s <<= 1) {
        const int u = (t >= s) ? lds[t - s] : 0;
        __syncthreads();
        lds[t] += u;
        __syncthreads();
    }
    const int excl = r0 + lds[t] - pd;
    cur[t] = excl;
    if (n0 + t < N_NODES) { offS[n0 + t] = excl; offE[n0 + t] = excl + pd; }
    // dummy tail (disjoint from scatter range; no extra sync needed)
    for (int i = excl + v; i < excl + pd; ++i)
        srcD[i] = make_int2(N_NODES, 0);
    __syncthreads();
    for (int i = r0 + t; i < r1; i += 256) {
        const unsigned rc = rec[i];
        const int dl  = (int)(rc >> 16);
        const int src = (int)(rc & 0xFFFFu);
        const float dx = pos[src * 3]     - dpx[dl];
        const float dy = pos[src * 3 + 1] - dpy[dl];
        const float dz = pos[src * 3 + 2] - dpz[dl];
        const float d  = dx * dx + dy * dy + dz * dz;
        const int p = atomicAdd(&cur[dl], 1);
        srcD[p] = make_int2(src, __float_as_int(d));
    }
}

// ---------------------------------------------------------------------------
// Aggregate: ONE NODE PER WAVE, 4 groups x 16 lanes (8 ch/lane), depth-2
// pipeline. Edge lists padded to x8 with inert dummies -> NO validity masks,
// NO prefetch clamps. Per edge: one 8B (src,dist) broadcast + one fp8 gather.
// ---------------------------------------------------------------------------
__global__ __launch_bounds__(256) void aggr_kernel(
    const unsigned char* __restrict__ Hsrc8, const __bf16* __restrict__ Hdst,
    const float*  __restrict__ Wmsg,
    const int*    __restrict__ offS, const int*   __restrict__ offE,
    const int2*   __restrict__ srcD, __bf16* __restrict__ aggrB)
{
    const int lane = threadIdx.x & 63;
    const int wv   = threadIdx.x >> 6;
    const int g    = lane >> 4;          // edge sub-group 0..3
    const int c8   = (lane & 15) * 8;    // channel base (8 ch/lane)

    float w2[8], hd[8], acc[8];
    *(f32x4*)&w2[0] = *(const f32x4*)(Wmsg + 256 * C + c8);
    *(f32x4*)&w2[4] = *(const f32x4*)(Wmsg + 256 * C + c8 + 4);

    const int n = blockIdx.x * 4 + wv;   // 12500*4 == 50000 exactly
    const int o0 = offS[n], o1 = offE[n];
    {   // unpack Hdst row slice (bf16 -> f32)
        const u32x4 hdb = *(const u32x4*)(Hdst + (long)n * C + c8);
        #pragma unroll
        for (int k = 0; k < 4; ++k) {
            hd[2*k]   = __uint_as_float(hdb[k] << 16);
            hd[2*k+1] = __uint_as_float(hdb[k] & 0xffff0000u);
        }
    }
    #pragma unroll
    for (int j = 0; j < 8; ++j) acc[j] = 0.f;

    if (o1 > o0) {
        int2 sd0 = srcD[o0 + g];
        int2 sd1 = srcD[o0 + 4 + g];
        for (int e = o0; e < o1; e += 8) {
            // issue both halves' gathers, then prefetch next (src,dist)
            const uint2 hu0 = *(const uint2*)(Hsrc8 + (long)sd0.x * C + c8);
            const uint2 hu1 = *(const uint2*)(Hsrc8 + (long)sd1.x * C + c8);
            const float d0 = __int_as_float(sd0.y);
            const float d1 = __int_as_float(sd1.y);
            const int2 sn0 = srcD[e + 8  + g];   // slack-guarded past last node
            const int2 sn1 = srcD[e + 12 + g];

            {   // half 0: edge e+g
                const f32x2 p0 = __builtin_amdgcn_cvt_pk_f32_fp8((int)hu0.x, false);
                const f32x2 p1 = __builtin_amdgcn_cvt_pk_f32_fp8((int)hu0.x, true);
                const f32x2 p2 = __builtin_amdgcn_cvt_pk_f32_fp8((int)hu0.y, false);
                const f32x2 p3 = __builtin_amdgcn_cvt_pk_f32_fp8((int)hu0.y, true);
                const float hs[8] = {p0[0],p0[1],p1[0],p1[1],p2[0],p2[1],p3[0],p3[1]};
                #pragma unroll
                for (int j = 0; j < 8; ++j)
                    acc[j] += fmaxf(hs[j] + fmaf(d0, w2[j], hd[j]), 0.f);
            }
            {   // half 1: edge e+4+g
                const f32x2 p0 = __builtin_amdgcn_cvt_pk_f32_fp8((int)hu1.x, false);
                const f32x2 p1 = __builtin_amdgcn_cvt_pk_f32_fp8((int)hu1.x, true);
                const f32x2 p2 = __builtin_amdgcn_cvt_pk_f32_fp8((int)hu1.y, false);
                const f32x2 p3 = __builtin_amdgcn_cvt_pk_f32_fp8((int)hu1.y, true);
                const float hs[8] = {p0[0],p0[1],p1[0],p1[1],p2[0],p2[1],p3[0],p3[1]};
                #pragma unroll
                for (int j = 0; j < 8; ++j)
                    acc[j] += fmaxf(hs[j] + fmaf(d1, w2[j], hd[j]), 0.f);
            }
            sd0 = sn0; sd1 = sn1;
        }
    }
    #pragma unroll
    for (int j = 0; j < 8; ++j) {        // combine the 4 edge groups
        acc[j] += __shfl_xor(acc[j], 16);
        acc[j] += __shfl_xor(acc[j], 32);
    }
    if (lane < 16) {
        bf16x8 v;
        #pragma unroll
        for (int j = 0; j < 8; ++j) v[j] = (__bf16)acc[j];
        *(bf16x8*)(aggrB + (long)n * C + c8) = v;
    }
}

// ---------------------------------------------------------------------------
// Node update: out = embed @ W_res + relu([embed, aggr] @ W_upd + b_upd)
// Reads pre-converted embedB (bf16) + aggrB (bf16). Grid 1024, ~3 tiles/block.
// ---------------------------------------------------------------------------
__global__ __launch_bounds__(512) void node_upd_kernel(
    const __bf16* __restrict__ embedB, const __bf16* __restrict__ aggrB,
    const float* __restrict__ Wres,  const float* __restrict__ Wupd,
    const float* __restrict__ bupd,  float* __restrict__ out)
{
    __shared__ short ldsF[16 * 256];

    const int t = threadIdx.x, lane = t & 63, wave = t >> 6;
    const int chbase = wave * 16, q = lane >> 4, nr = lane & 15;

    bf16x8 aU[8], aR[4];
    {
        const int ch = chbase + nr;
        #pragma unroll
        for (int ks = 0; ks < 8; ++ks)
            #pragma unroll
            for (int i = 0; i < 8; ++i)
                aU[ks][i] = (__bf16)Wupd[(ks*32 + q*8 + i) * C + ch];
        #pragma unroll
        for (int ks = 0; ks < 4; ++ks)
            #pragma unroll
            for (int i = 0; i < 8; ++i)
                aR[ks][i] = (__bf16)Wres[(ks*32 + q*8 + i) * C + ch];
    }
    float bu[4];
    #pragma unroll
    for (int r = 0; r < 4; ++r) bu[r] = bupd[chbase + q*4 + r];

    for (int nt = blockIdx.x; nt < NTILES; nt += gridDim.x) {
        const int n0 = nt * 16;
        {   // stage [embedB | aggrB] (both bf16 copies) for 16 nodes
            const int nn = t >> 5, seg = t & 31;
            const __bf16* base = (seg < 16) ? embedB : aggrB;
            const bf16x8 v = *(const bf16x8*)(base + (long)(n0 + nn) * C + (seg & 15) * 8);
            *(bf16x8*)(&ldsF[swz8(nn, seg * 8)]) = v;
        }
        __syncthreads();

        f32x4 au = {0.f,0.f,0.f,0.f}, ar = {0.f,0.f,0.f,0.f};
        #pragma unroll
        for (int ks = 0; ks < 8; ++ks) {
            const bf16x8 b = *(const bf16x8*)(&ldsF[swz8(nr, ks * 32 + q * 8)]);
            au = __builtin_amdgcn_mfma_f32_16x16x32_bf16(aU[ks], b, au, 0, 0, 0);
        }
        #pragma unroll
        for (int ks = 0; ks < 4; ++ks) {
            const bf16x8 b = *(const bf16x8*)(&ldsF[swz8(nr, ks * 32 + q * 8)]);
            ar = __builtin_amdgcn_mfma_f32_16x16x32_bf16(aR[ks], b, ar, 0, 0, 0);
        }
        __syncthreads();

        const int node = n0 + nr;
        float* dst = out + (long)node * C + chbase + q * 4;
        #pragma unroll
        for (int r = 0; r < 4; ++r)
            dst[r] = ar[r] + fmaxf(au[r] + bu[r], 0.f);
    }
}

extern "C" void kernel_launch(void* const* d_in, const int* in_sizes, int n_in,
                              void* d_out, int out_size, void* d_ws, size_t ws_size,
                              hipStream_t stream) {
    const float* embed = (const float*)d_in[0];
    const float* pos   = (const float*)d_in[1];
    const float* Wres  = (const float*)d_in[2];
    const float* Wmsg  = (const float*)d_in[3];
    const float* bmsg  = (const float*)d_in[4];
    const float* Wupd  = (const float*)d_in[5];
    const float* bupd  = (const float*)d_in[6];
    const int*   eidx  = (const int*)d_in[7];
    float* out = (float*)d_out;

    char* ws = (char*)d_ws;
    int*            gcur  = (int*)(ws + WS_GCUR);
    int*            offS  = (int*)(ws + WS_OFFS);
    int*            offE  = (int*)(ws + WS_OFFE);
    int2*           srcD  = (int2*)(ws + WS_SRCD);
    unsigned*       rec   = (unsigned*)(ws + WS_REC);
    __bf16*         HdstB = (__bf16*)(ws + WS_HDST);
    unsigned char*  Hsrc8 = (unsigned char*)(ws + WS_HSRC8);
    __bf16*         embB  = (__bf16*)(ws + WS_EMBB);
    __bf16*         aggrB = (__bf16*)(ws + WS_AGGR);

    precomp_kernel<<<1024, 512, 0, stream>>>(embed, Wmsg, bmsg, Hsrc8, HdstB, embB, gcur);
    partition_kernel<<<N_EDGES / 1024, 256, 0, stream>>>(eidx, gcur, rec);
    bucket_csr_kernel<<<NB, 256, 0, stream>>>(rec, gcur, pos, offS, offE, srcD);
    aggr_kernel<<<N_NODES / 4, 256, 0, stream>>>(Hsrc8, HdstB, Wmsg, offS, offE, srcD, aggrB);
    node_upd_kernel<<<1024, 512, 0, stream>>>(embB, aggrB, Wres, Wupd, bupd, out);
}

// Round 15
// 94.699 us; speedup vs baseline: 1.4342x; 1.0378x over previous
//
#include <hip/hip_runtime.h>
#include <hip/hip_bf16.h>

#define N_NODES 50000
#define N_EDGES 640000
#define C 128            // IN_C == HID
#define NB 196           // dst buckets of 256 nodes (50000 <= 196*256)
#define BCAP 5120        // per-bucket slot (raw mean 3277, padded mean 4199, +15 sigma)
#define NTILES (N_NODES / 16)                               // 3125

typedef __bf16 bf16x8 __attribute__((ext_vector_type(8)));
typedef __bf16 bf16x4 __attribute__((ext_vector_type(4)));
typedef float  f32x4  __attribute__((ext_vector_type(4)));
typedef float  f32x2  __attribute__((ext_vector_type(2)));
typedef unsigned int u32x4 __attribute__((ext_vector_type(4)));

// ---- d_ws layout (byte offsets) ----
#define WS_GCUR   0          // NB ints (bucket cursors; zeroed by precomp blk0)
#define WS_OFFS   1024       // N ints (padded range start)
#define WS_OFFE   201216     // N ints (padded range end)
#define WS_SRCD   401408     // NB*BCAP int2 + slack (src id, dist bits)
#define WS_REC    8429824    // NB*BCAP u32 packed records (src | dstLocal<<16)
#define WS_HDST   12443904   // N*C bf16 (Hdst + bias)
#define WS_HSRC8  25243904   // (N+1)*C fp8 e4m3 (row N = dummy, all 0xFE)
#define WS_EMBB   31644160   // N*C bf16 (embed, pre-converted)
#define WS_AGGR   44444160   // N*C bf16 (aggregation result)
// total ~57.2 MB

// XOR-swizzle for [16][128]-short LDS tiles (2-way residual conflict = free).
__device__ __forceinline__ int swzS(int row, int soff) {
    return row * 128 + (soff ^ ((row & 7) << 3));
}
// [16][256]-short variant (node-update staging)
__device__ __forceinline__ int swz8(int row, int soff) {
    return row * 256 + (soff ^ ((row & 7) << 3));
}

// ---------------------------------------------------------------------------
// Precompute Hsrc = embed @ Wmsg[0:128]          (fp8 e4m3, ws)
//            Hdst = embed @ Wmsg[128:256] + b    (bf16, ws)
//            embedB = bf16(embed)                (free: staging regs re-stored)
// Block 0 zeroes gcur and writes the dummy Hsrc8 row (0xFE = -448 fp8).
// ---------------------------------------------------------------------------
__global__ __launch_bounds__(512) void precomp_kernel(
    const float* __restrict__ embed, const float* __restrict__ Wmsg,
    const float* __restrict__ bmsg,  unsigned char* __restrict__ Hsrc8,
    __bf16* __restrict__ Hdst, __bf16* __restrict__ embedB,
    int* __restrict__ gcur)
{
    __shared__ short lds[16 * 128];

    const int t = threadIdx.x, lane = t & 63, wave = t >> 6;
    const int chbase = wave * 16, q = lane >> 4, nr = lane & 15;
    const int ch = chbase + nr;

    if (blockIdx.x == 0) {
        if (t < NB) gcur[t] = 0;
        if (t < 16)  // dummy row: relu(-448 + hd + 0) == 0 for any real hd
            *(unsigned long long*)(Hsrc8 + (long)N_NODES * C + t * 8) =
                0xFEFEFEFEFEFEFEFEULL;
    }

    bf16x8 aS[4], aD[4];
    #pragma unroll
    for (int ks = 0; ks < 4; ++ks)
        #pragma unroll
        for (int i = 0; i < 8; ++i) {
            const int k = ks * 32 + q * 8 + i;
            aS[ks][i] = (__bf16)Wmsg[k * C + ch];
            aD[ks][i] = (__bf16)Wmsg[(128 + k) * C + ch];
        }
    float bias[4];
    #pragma unroll
    for (int r = 0; r < 4; ++r) bias[r] = bmsg[chbase + q * 4 + r];

    for (int nt = blockIdx.x; nt < NTILES; nt += gridDim.x) {
        const int n0 = nt * 16;
        {   // stage 16 nodes x 128 feats: f32 -> bf16 LDS (+ store embedB copy)
            const int row = t >> 5, seg = t & 31;
            const float4 f = *(const float4*)(embed + (long)(n0 + row) * C + seg * 4);
            bf16x4 v;
            v[0]=(__bf16)f.x; v[1]=(__bf16)f.y; v[2]=(__bf16)f.z; v[3]=(__bf16)f.w;
            *(bf16x4*)(&lds[swzS(row, seg * 4)]) = v;
            *(bf16x4*)(embedB + (long)(n0 + row) * C + seg * 4) = v;
        }
        __syncthreads();

        f32x4 hs = {0.f,0.f,0.f,0.f}, hd = {0.f,0.f,0.f,0.f};
        #pragma unroll
        for (int ks = 0; ks < 4; ++ks) {
            const bf16x8 b = *(const bf16x8*)(&lds[swzS(nr, ks * 32 + q * 8)]);
            hs = __builtin_amdgcn_mfma_f32_16x16x32_bf16(aS[ks], b, hs, 0, 0, 0);
            hd = __builtin_amdgcn_mfma_f32_16x16x32_bf16(aD[ks], b, hd, 0, 0, 0);
        }
        __syncthreads();

        const int node = n0 + nr;            // D: col=node, row(q*4+r)=ch
        int w8 = 0;
        w8 = __builtin_amdgcn_cvt_pk_fp8_f32(hs[0], hs[1], w8, false);
        w8 = __builtin_amdgcn_cvt_pk_fp8_f32(hs[2], hs[3], w8, true);
        *(unsigned*)(Hsrc8 + (long)node * C + chbase + q * 4) = (unsigned)w8;
        bf16x4 vd;
        #pragma unroll
        for (int r = 0; r < 4; ++r) vd[r] = (__bf16)(hd[r] + bias[r]);
        *(bf16x4*)(Hdst + (long)node * C + chbase + q * 4) = vd;
    }
}

// ---------------------------------------------------------------------------
// partition: bin 1024 edges/block by dst>>8 via LDS counters; reserve a range
// in the bucket's FIXED slot [b*BCAP, (b+1)*BCAP) with one global atomic per
// bucket per block; write packed 4B records (src | dstLocal<<16).
// ---------------------------------------------------------------------------
__global__ __launch_bounds__(256) void partition_kernel(
    const int* __restrict__ eidx, int* __restrict__ gcur,
    unsigned* __restrict__ rec)
{
    __shared__ int cnt[NB];
    __shared__ int base[NB];
    const int t = threadIdx.x;
    if (t < NB) cnt[t] = 0;
    __syncthreads();
    const int e0 = blockIdx.x * 1024;
    int lrank[4], bb[4];
    unsigned prec[4];
    #pragma unroll
    for (int k = 0; k < 4; ++k) {
        const int e = e0 + k * 256 + t;
        const int r = eidx[e], c = eidx[N_EDGES + e];
        bb[k]   = c >> 8;
        prec[k] = (unsigned)r | ((unsigned)(c & 255) << 16);
        lrank[k] = atomicAdd(&cnt[bb[k]], 1);
    }
    __syncthreads();
    if (t < NB) base[t] = t * BCAP + atomicAdd(&gcur[t], cnt[t]);
    __syncthreads();
    #pragma unroll
    for (int k = 0; k < 4; ++k)
        rec[base[bb[k]] + lrank[k]] = prec[k];
}

// ---------------------------------------------------------------------------
// bucket_csr: one block per bucket. LDS deg-count -> scan of PADDED degrees
// (multiple of 8) -> offS/offE; scatter (src, dist) pairs; fill each node's
// tail [offS+deg, offS+pdeg) with dummy records (src=N_NODES, d=0).
// ---------------------------------------------------------------------------
__global__ __launch_bounds__(256) void bucket_csr_kernel(
    const unsigned* __restrict__ rec, const int* __restrict__ gcur,
    const float* __restrict__ pos, int* __restrict__ offS,
    int* __restrict__ offE, int2* __restrict__ srcD)
{
    __shared__ int   deg[256];
    __shared__ int   cur[256];
    __shared__ int   lds[256];
    __shared__ float dpx[256], dpy[256], dpz[256];
    const int t = threadIdx.x, b = blockIdx.x;
    const int r0 = b * BCAP, r1 = r0 + gcur[b], n0 = b << 8;
    deg[t] = 0;
    {   // stage this bucket's 256 dst positions
        const int nn = n0 + t;
        const int cl = min(nn, N_NODES - 1);
        dpx[t] = pos[cl * 3]; dpy[t] = pos[cl * 3 + 1]; dpz[t] = pos[cl * 3 + 2];
    }
    __syncthreads();
    for (int i = r0 + t; i < r1; i += 256)
        atomicAdd(&deg[rec[i] >> 16], 1);
    __syncthreads();
    const int v  = deg[t];
    const int pd = (v + 7) & ~7;          // pad to multiple of 8
    lds[t] = pd;
    __syncthreads();
    for (int s = 1; s < 256; s <<= 1) {
        const int u = (t >= s) ? lds[t - s] : 0;
        __syncthreads();
        lds[t] += u;
        __syncthreads();
    }
    const int excl = r0 + lds[t] - pd;
    cur[t] = excl;
    if (n0 + t < N_NODES) { offS[n0 + t] = excl; offE[n0 + t] = excl + pd; }
    // dummy tail (disjoint from scatter range; no extra sync needed)
    for (int i = excl + v; i < excl + pd; ++i)
        srcD[i] = make_int2(N_NODES, 0);
    __syncthreads();
    for (int i = r0 + t; i < r1; i += 256) {
        const unsigned rc = rec[i];
        const int dl  = (int)(rc >> 16);
        const int src = (int)(rc & 0xFFFFu);
        const float dx = pos[src * 3]     - dpx[dl];
        const float dy = pos[src * 3 + 1] - dpy[dl];
        const float dz = pos[src * 3 + 2] - dpz[dl];
        const float d  = dx * dx + dy * dy + dz * dz;
        const int p = atomicAdd(&cur[dl], 1);
        srcD[p] = make_int2(src, __float_as_int(d));
    }
}

// ---------------------------------------------------------------------------
// Aggregate: ONE NODE PER WAVE, 4 groups x 16 lanes (8 ch/lane), 2-stage
// SOFTWARE PIPELINE: iteration i issues iteration i+1's Hsrc gathers (ids
// loaded two iterations ahead). Padded lists -> no masks/clamps on consume;
// issued-early gather index clamped to the dummy row (stale past-end ids).
// ---------------------------------------------------------------------------
__global__ __launch_bounds__(256) void aggr_kernel(
    const unsigned char* __restrict__ Hsrc8, const __bf16* __restrict__ Hdst,
    const float*  __restrict__ Wmsg,
    const int*    __restrict__ offS, const int*   __restrict__ offE,
    const int2*   __restrict__ srcD, __bf16* __restrict__ aggrB)
{
    const int lane = threadIdx.x & 63;
    const int wv   = threadIdx.x >> 6;
    const int g    = lane >> 4;          // edge sub-group 0..3
    const int c8   = (lane & 15) * 8;    // channel base (8 ch/lane)

    float w2[8], hd[8], acc[8];
    *(f32x4*)&w2[0] = *(const f32x4*)(Wmsg + 256 * C + c8);
    *(f32x4*)&w2[4] = *(const f32x4*)(Wmsg + 256 * C + c8 + 4);

    const int n = blockIdx.x * 4 + wv;   // 12500*4 == 50000 exactly
    const int o0 = offS[n], o1 = offE[n];
    {   // unpack Hdst row slice (bf16 -> f32)
        const u32x4 hdb = *(const u32x4*)(Hdst + (long)n * C + c8);
        #pragma unroll
        for (int k = 0; k < 4; ++k) {
            hd[2*k]   = __uint_as_float(hdb[k] << 16);
            hd[2*k+1] = __uint_as_float(hdb[k] & 0xffff0000u);
        }
    }
    #pragma unroll
    for (int j = 0; j < 8; ++j) acc[j] = 0.f;

    if (o1 > o0) {
        // pipeline fill: iter0 ids + gathers, iter1 ids
        int2 sdA0 = srcD[o0 + g];
        int2 sdA1 = srcD[o0 + 4 + g];
        uint2 huA0 = *(const uint2*)(Hsrc8 + (long)sdA0.x * C + c8);
        uint2 huA1 = *(const uint2*)(Hsrc8 + (long)sdA1.x * C + c8);
        int2 sdB0 = srcD[o0 + 8 + g];
        int2 sdB1 = srcD[o0 + 12 + g];
        for (int e = o0; e < o1; e += 8) {
            // issue NEXT iteration's gathers (clamped: past-end prefetch may
            // hold stale ids -> redirect to the inert dummy row)
            const long bx0 = (long)min((unsigned)sdB0.x, (unsigned)N_NODES);
            const long bx1 = (long)min((unsigned)sdB1.x, (unsigned)N_NODES);
            const uint2 huB0 = *(const uint2*)(Hsrc8 + bx0 * C + c8);
            const uint2 huB1 = *(const uint2*)(Hsrc8 + bx1 * C + c8);
            // load iter+2 ids (srcD has >=96B slack past the last region)
            const int2 sdC0 = srcD[e + 16 + g];
            const int2 sdC1 = srcD[e + 20 + g];
            const float d0 = __int_as_float(sdA0.y);
            const float d1 = __int_as_float(sdA1.y);

            {   // consume half 0: edge e+g
                const f32x2 p0 = __builtin_amdgcn_cvt_pk_f32_fp8((int)huA0.x, false);
                const f32x2 p1 = __builtin_amdgcn_cvt_pk_f32_fp8((int)huA0.x, true);
                const f32x2 p2 = __builtin_amdgcn_cvt_pk_f32_fp8((int)huA0.y, false);
                const f32x2 p3 = __builtin_amdgcn_cvt_pk_f32_fp8((int)huA0.y, true);
                const float hs[8] = {p0[0],p0[1],p1[0],p1[1],p2[0],p2[1],p3[0],p3[1]};
                #pragma unroll
                for (int j = 0; j < 8; ++j)
                    acc[j] += fmaxf(hs[j] + fmaf(d0, w2[j], hd[j]), 0.f);
            }
            {   // consume half 1: edge e+4+g
                const f32x2 p0 = __builtin_amdgcn_cvt_pk_f32_fp8((int)huA1.x, false);
                const f32x2 p1 = __builtin_amdgcn_cvt_pk_f32_fp8((int)huA1.x, true);
                const f32x2 p2 = __builtin_amdgcn_cvt_pk_f32_fp8((int)huA1.y, false);
                const f32x2 p3 = __builtin_amdgcn_cvt_pk_f32_fp8((int)huA1.y, true);
                const float hs[8] = {p0[0],p0[1],p1[0],p1[1],p2[0],p2[1],p3[0],p3[1]};
                #pragma unroll
                for (int j = 0; j < 8; ++j)
                    acc[j] += fmaxf(hs[j] + fmaf(d1, w2[j], hd[j]), 0.f);
            }
            // shift pipeline
            sdA0 = sdB0; sdA1 = sdB1; sdB0 = sdC0; sdB1 = sdC1;
            huA0 = huB0; huA1 = huB1;
        }
    }
    #pragma unroll
    for (int j = 0; j < 8; ++j) {        // combine the 4 edge groups
        acc[j] += __shfl_xor(acc[j], 16);
        acc[j] += __shfl_xor(acc[j], 32);
    }
    if (lane < 16) {
        bf16x8 v;
        #pragma unroll
        for (int j = 0; j < 8; ++j) v[j] = (__bf16)acc[j];
        *(bf16x8*)(aggrB + (long)n * C + c8) = v;
    }
}

// ---------------------------------------------------------------------------
// Node update: out = embed @ W_res + relu([embed, aggr] @ W_upd + b_upd)
// Reads pre-converted embedB (bf16) + aggrB (bf16). Grid 512 (~6 tiles/block
// amortizes the 96-value weight fragment load; halves L2 weight traffic).
// ---------------------------------------------------------------------------
__global__ __launch_bounds__(512) void node_upd_kernel(
    const __bf16* __restrict__ embedB, const __bf16* __restrict__ aggrB,
    const float* __restrict__ Wres,  const float* __restrict__ Wupd,
    const float* __restrict__ bupd,  float* __restrict__ out)
{
    __shared__ short ldsF[16 * 256];

    const int t = threadIdx.x, lane = t & 63, wave = t >> 6;
    const int chbase = wave * 16, q = lane >> 4, nr = lane & 15;

    bf16x8 aU[8], aR[4];
    {
        const int ch = chbase + nr;
        #pragma unroll
        for (int ks = 0; ks < 8; ++ks)
            #pragma unroll
            for (int i = 0; i < 8; ++i)
                aU[ks][i] = (__bf16)Wupd[(ks*32 + q*8 + i) * C + ch];
        #pragma unroll
        for (int ks = 0; ks < 4; ++ks)
            #pragma unroll
            for (int i = 0; i < 8; ++i)
                aR[ks][i] = (__bf16)Wres[(ks*32 + q*8 + i) * C + ch];
    }
    float bu[4];
    #pragma unroll
    for (int r = 0; r < 4; ++r) bu[r] = bupd[chbase + q*4 + r];

    for (int nt = blockIdx.x; nt < NTILES; nt += gridDim.x) {
        const int n0 = nt * 16;
        {   // stage [embedB | aggrB] (both bf16 copies) for 16 nodes
            const int nn = t >> 5, seg = t & 31;
            const __bf16* base = (seg < 16) ? embedB : aggrB;
            const bf16x8 v = *(const bf16x8*)(base + (long)(n0 + nn) * C + (seg & 15) * 8);
            *(bf16x8*)(&ldsF[swz8(nn, seg * 8)]) = v;
        }
        __syncthreads();

        f32x4 au = {0.f,0.f,0.f,0.f}, ar = {0.f,0.f,0.f,0.f};
        #pragma unroll
        for (int ks = 0; ks < 8; ++ks) {
            const bf16x8 b = *(const bf16x8*)(&ldsF[swz8(nr, ks * 32 + q * 8)]);
            au = __builtin_amdgcn_mfma_f32_16x16x32_bf16(aU[ks], b, au, 0, 0, 0);
        }
        #pragma unroll
        for (int ks = 0; ks < 4; ++ks) {
            const bf16x8 b = *(const bf16x8*)(&ldsF[swz8(nr, ks * 32 + q * 8)]);
            ar = __builtin_amdgcn_mfma_f32_16x16x32_bf16(aR[ks], b, ar, 0, 0, 0);
        }
        __syncthreads();

        const int node = n0 + nr;
        float* dst = out + (long)node * C + chbase + q * 4;
        #pragma unroll
        for (int r = 0; r < 4; ++r)
            dst[r] = ar[r] + fmaxf(au[r] + bu[r], 0.f);
    }
}

extern "C" void kernel_launch(void* const* d_in, const int* in_sizes, int n_in,
                              void* d_out, int out_size, void* d_ws, size_t ws_size,
                              hipStream_t stream) {
    const float* embed = (const float*)d_in[0];
    const float* pos   = (const float*)d_in[1];
    const float* Wres  = (const float*)d_in[2];
    const float* Wmsg  = (const float*)d_in[3];
    const float* bmsg  = (const float*)d_in[4];
    const float* Wupd  = (const float*)d_in[5];
    const float* bupd  = (const float*)d_in[6];
    const int*   eidx  = (const int*)d_in[7];
    float* out = (float*)d_out;

    char* ws = (char*)d_ws;
    int*            gcur  = (int*)(ws + WS_GCUR);
    int*            offS  = (int*)(ws + WS_OFFS);
    int*            offE  = (int*)(ws + WS_OFFE);
    int2*           srcD  = (int2*)(ws + WS_SRCD);
    unsigned*       rec   = (unsigned*)(ws + WS_REC);
    __bf16*         HdstB = (__bf16*)(ws + WS_HDST);
    unsigned char*  Hsrc8 = (unsigned char*)(ws + WS_HSRC8);
    __bf16*         embB  = (__bf16*)(ws + WS_EMBB);
    __bf16*         aggrB = (__bf16*)(ws + WS_AGGR);

    precomp_kernel<<<1024, 512, 0, stream>>>(embed, Wmsg, bmsg, Hsrc8, HdstB, embB, gcur);
    partition_kernel<<<N_EDGES / 1024, 256, 0, stream>>>(eidx, gcur, rec);
    bucket_csr_kernel<<<NB, 256, 0, stream>>>(rec, gcur, pos, offS, offE, srcD);
    aggr_kernel<<<N_NODES / 4, 256, 0, stream>>>(Hsrc8, HdstB, Wmsg, offS, offE, srcD, aggrB);
    node_upd_kernel<<<512, 512, 0, stream>>>(embB, aggrB, Wres, Wupd, bupd, out);
}